// Round 1
// baseline (938.318 us; speedup 1.0000x reference)
//
#include <hip/hip_runtime.h>
#include <hip/hip_bf16.h>
#include <cstdint>

#define NNODES 100000
#define NEDGES 1000000
#define HDIM 64
#define ODIM 16
#define NB 8

__device__ __forceinline__ float asf(uint32_t u) { float f; __builtin_memcpy(&f, &u, 4); return f; }
__device__ __forceinline__ uint32_t asu(float f) { uint32_t u; __builtin_memcpy(&u, &f, 4); return u; }
// round-to-nearest-even f32 -> bf16
__device__ __forceinline__ uint16_t f2bf(float f) {
    uint32_t x = asu(f);
    return (uint16_t)((x + 0x7FFFu + ((x >> 16) & 1u)) >> 16);
}
__device__ __forceinline__ uint32_t pack2(float lo, float hi) {
    return (uint32_t)f2bf(lo) | ((uint32_t)f2bf(hi) << 16);
}

// ---------------------------------------------------------------------------
// Projection: Hn[n][o][b] = sum_i x[n][i] * bases[b][i][o]   (bf16 out)
// Whole layer weight lives in LDS as bf16 [i][o][b] (64*DOUT*8*2 bytes).
// Thread t -> o = t%DOUT, ns = t/DOUT; 4 nodes/thread, 8 basis accums/node.
// ---------------------------------------------------------------------------
template <int DOUT, bool RELU>
__launch_bounds__(256)
__global__ void project_kernel(const float* __restrict__ x,
                               const float* __restrict__ bases,
                               uint16_t* __restrict__ hn, int nNodes) {
    constexpr int SUBS = 256 / DOUT;   // node sub-slots per tile pass
    constexpr int NPT  = 4;            // nodes per thread
    constexpr int TILE = SUBS * NPT;   // nodes per block-tile
    constexpr int XS   = HDIM + 1;     // padded x row (bank-conflict break)

    __shared__ __align__(16) uint16_t Wl[HDIM * DOUT * NB];
    __shared__ __align__(16) float    Xl[TILE * XS];

    const int t  = threadIdx.x;
    const int o  = t % DOUT;
    const int ns = t / DOUT;

    // Stage weights once per block: global [b][i][o] f32 -> LDS [i][o][b] bf16
    for (int idx = t; idx < HDIM * DOUT * NB; idx += 256) {
        int b   = idx / (HDIM * DOUT);
        int rem = idx - b * (HDIM * DOUT);
        int i   = rem / DOUT;
        int oo  = rem - i * DOUT;
        Wl[(i * DOUT + oo) * NB + b] = f2bf(bases[idx]);
    }

    const int numTiles = (nNodes + TILE - 1) / TILE;
    for (int tile = blockIdx.x; tile < numTiles; tile += gridDim.x) {
        const int n0 = tile * TILE;
        __syncthreads();  // W ready (first iter) / Xl readers done (later iters)
        for (int idx = t; idx < TILE * HDIM; idx += 256) {
            int nn = idx / HDIM, i = idx - nn * HDIM;
            int g = n0 + nn;
            float v = (g < nNodes) ? x[(size_t)g * HDIM + i] : 0.f;
            if (RELU) v = fmaxf(v, 0.f);
            Xl[nn * XS + i] = v;
        }
        __syncthreads();

        float acc[NPT][NB];
#pragma unroll
        for (int k = 0; k < NPT; k++)
#pragma unroll
            for (int b = 0; b < NB; b++) acc[k][b] = 0.f;

#pragma unroll 8
        for (int i = 0; i < HDIM; i++) {
            const uint4 wv = *reinterpret_cast<const uint4*>(Wl + (i * DOUT + o) * NB);
            float w[NB];
            w[0] = asf(wv.x << 16); w[1] = asf(wv.x & 0xFFFF0000u);
            w[2] = asf(wv.y << 16); w[3] = asf(wv.y & 0xFFFF0000u);
            w[4] = asf(wv.z << 16); w[5] = asf(wv.z & 0xFFFF0000u);
            w[6] = asf(wv.w << 16); w[7] = asf(wv.w & 0xFFFF0000u);
#pragma unroll
            for (int k = 0; k < NPT; k++) {
                const float xv = Xl[(k * SUBS + ns) * XS + i];
#pragma unroll
                for (int b = 0; b < NB; b++) acc[k][b] = fmaf(xv, w[b], acc[k][b]);
            }
        }

#pragma unroll
        for (int k = 0; k < NPT; k++) {
            const int g = n0 + k * SUBS + ns;
            if (g < nNodes) {
                uint4 pv;
                pv.x = pack2(acc[k][0], acc[k][1]);
                pv.y = pack2(acc[k][2], acc[k][3]);
                pv.z = pack2(acc[k][4], acc[k][5]);
                pv.w = pack2(acc[k][6], acc[k][7]);
                *reinterpret_cast<uint4*>(hn + ((size_t)g * DOUT + o) * NB) = pv;
            }
        }
    }
}

// ---------------------------------------------------------------------------
// Edge aggregation, DOUT=64: one wave per edge, lane = output element.
// Gather = one uint4 (8 bf16 bases) per lane = 1KB coalesced per edge.
// ---------------------------------------------------------------------------
__launch_bounds__(256)
__global__ void edge_kernel64(const uint16_t* __restrict__ hn,
                              const float* __restrict__ coeff,
                              const int* __restrict__ src, const int* __restrict__ dst,
                              const int* __restrict__ et, const float* __restrict__ norm,
                              float* __restrict__ out, int nEdges) {
    const int lane = threadIdx.x & 63;
    const int wid  = (int)((blockIdx.x * blockDim.x + threadIdx.x) >> 6);
    const int nw   = (int)((gridDim.x * blockDim.x) >> 6);
    for (int e = wid; e < nEdges; e += nw) {
        const int s = src[e], d = dst[e], r = et[e];
        const float nm = norm[e];
        const float4 cA = *reinterpret_cast<const float4*>(coeff + r * NB);
        const float4 cB = *reinterpret_cast<const float4*>(coeff + r * NB + 4);
        const uint4 hv = *reinterpret_cast<const uint4*>(hn + ((size_t)s * HDIM + lane) * NB);
        float acc;
        acc  = cA.x * asf(hv.x << 16);
        acc += cA.y * asf(hv.x & 0xFFFF0000u);
        acc += cA.z * asf(hv.y << 16);
        acc += cA.w * asf(hv.y & 0xFFFF0000u);
        acc += cB.x * asf(hv.z << 16);
        acc += cB.y * asf(hv.z & 0xFFFF0000u);
        acc += cB.z * asf(hv.w << 16);
        acc += cB.w * asf(hv.w & 0xFFFF0000u);
        unsafeAtomicAdd(out + (size_t)d * HDIM + lane, nm * acc);
    }
}

// DOUT=16: quarter-wave (16 lanes) per edge.
__launch_bounds__(256)
__global__ void edge_kernel16(const uint16_t* __restrict__ hn,
                              const float* __restrict__ coeff,
                              const int* __restrict__ src, const int* __restrict__ dst,
                              const int* __restrict__ et, const float* __restrict__ norm,
                              float* __restrict__ out, int nEdges) {
    const int g    = (int)(blockIdx.x * blockDim.x + threadIdx.x);
    const int lane = g & 15;
    const int qid  = g >> 4;
    const int nq   = (int)((gridDim.x * blockDim.x) >> 4);
    for (int e = qid; e < nEdges; e += nq) {
        const int s = src[e], d = dst[e], r = et[e];
        const float nm = norm[e];
        const float4 cA = *reinterpret_cast<const float4*>(coeff + r * NB);
        const float4 cB = *reinterpret_cast<const float4*>(coeff + r * NB + 4);
        const uint4 hv = *reinterpret_cast<const uint4*>(hn + ((size_t)s * ODIM + lane) * NB);
        float acc;
        acc  = cA.x * asf(hv.x << 16);
        acc += cA.y * asf(hv.x & 0xFFFF0000u);
        acc += cA.z * asf(hv.y << 16);
        acc += cA.w * asf(hv.y & 0xFFFF0000u);
        acc += cB.x * asf(hv.z << 16);
        acc += cB.y * asf(hv.z & 0xFFFF0000u);
        acc += cB.z * asf(hv.w << 16);
        acc += cB.w * asf(hv.w & 0xFFFF0000u);
        unsafeAtomicAdd(out + (size_t)d * ODIM + lane, nm * acc);
    }
}

// Init accumulator buffer with broadcast bias (bias add folded into init).
template <int D>
__global__ void fill_bias_kernel(float* __restrict__ out, const float* __restrict__ bias,
                                 int total) {
    const int stride = (int)(gridDim.x * blockDim.x);
    for (int i = (int)(blockIdx.x * blockDim.x + threadIdx.x); i < total; i += stride)
        out[i] = bias[i & (D - 1)];
}

extern "C" void kernel_launch(void* const* d_in, const int* in_sizes, int n_in,
                              void* d_out, int out_size, void* d_ws, size_t ws_size,
                              hipStream_t stream) {
    const float* feats  = (const float*)d_in[0];
    const float* coeff0 = (const float*)d_in[1];
    const float* bases0 = (const float*)d_in[2];
    const float* bias0  = (const float*)d_in[3];
    const float* coeff1 = (const float*)d_in[4];
    const float* bases1 = (const float*)d_in[5];
    const float* bias1  = (const float*)d_in[6];
    const float* coeff2 = (const float*)d_in[7];
    const float* bases2 = (const float*)d_in[8];
    const float* bias2  = (const float*)d_in[9];
    const int*   src    = (const int*)d_in[10];
    const int*   dst    = (const int*)d_in[11];
    const int*   etype  = (const int*)d_in[12];
    const float* norm   = (const float*)d_in[13];
    float* out = (float*)d_out;

    // ws layout: [0, 102.4MB) Hn (bf16, reused L0/L1 as [N][64][8], L2 as [N][16][8])
    //            [102.4MB, 128MB) h accumulator (f32 [N][64], reused L0->L1)
    uint16_t* hn = (uint16_t*)d_ws;
    float*    h  = (float*)((char*)d_ws + (size_t)NNODES * HDIM * NB * 2);

    // ---- Layer 0: feats -> h (relu folded into next projection's load)
    hipLaunchKernelGGL((project_kernel<64, false>), dim3(2048), dim3(256), 0, stream,
                       feats, bases0, hn, NNODES);
    hipLaunchKernelGGL((fill_bias_kernel<64>), dim3(1024), dim3(256), 0, stream,
                       h, bias0, NNODES * HDIM);
    hipLaunchKernelGGL(edge_kernel64, dim3(4096), dim3(256), 0, stream,
                       hn, coeff0, src, dst, etype, norm, h, NEDGES);

    // ---- Layer 1: h -> h   (project reads h w/ relu BEFORE fill overwrites it)
    hipLaunchKernelGGL((project_kernel<64, true>), dim3(2048), dim3(256), 0, stream,
                       h, bases1, hn, NNODES);
    hipLaunchKernelGGL((fill_bias_kernel<64>), dim3(1024), dim3(256), 0, stream,
                       h, bias1, NNODES * HDIM);
    hipLaunchKernelGGL(edge_kernel64, dim3(4096), dim3(256), 0, stream,
                       hn, coeff1, src, dst, etype, norm, h, NEDGES);

    // ---- Layer 2: h -> out (no relu on output)
    hipLaunchKernelGGL((project_kernel<16, true>), dim3(1024), dim3(256), 0, stream,
                       h, bases2, hn, NNODES);
    hipLaunchKernelGGL((fill_bias_kernel<16>), dim3(1024), dim3(256), 0, stream,
                       out, bias2, NNODES * ODIM);
    hipLaunchKernelGGL(edge_kernel16, dim3(4096), dim3(256), 0, stream,
                       hn, coeff2, src, dst, etype, norm, out, NEDGES);
}

// Round 2
// 832.866 us; speedup vs baseline: 1.1266x; 1.1266x over previous
//
#include <hip/hip_runtime.h>
#include <hip/hip_bf16.h>
#include <cstdint>

#define NNODES 100000
#define NEDGES 1000000
#define HDIM 64
#define ODIM 16
#define NB 8

__device__ __forceinline__ float asf(uint32_t u) { float f; __builtin_memcpy(&f, &u, 4); return f; }
__device__ __forceinline__ uint32_t asu(float f) { uint32_t u; __builtin_memcpy(&u, &f, 4); return u; }
__device__ __forceinline__ uint16_t f2bf(float f) {
    uint32_t x = asu(f);
    return (uint16_t)((x + 0x7FFFu + ((x >> 16) & 1u)) >> 16);
}
__device__ __forceinline__ uint32_t pack2(float lo, float hi) {
    return (uint32_t)f2bf(lo) | ((uint32_t)f2bf(hi) << 16);
}
// dot of 8 coeffs with 8 bf16 values packed in a uint4
__device__ __forceinline__ float dot8(const float4& cA, const float4& cB, const uint4& hv) {
    float a;
    a = cA.x * asf(hv.x << 16);
    a = fmaf(cA.y, asf(hv.x & 0xFFFF0000u), a);
    a = fmaf(cA.z, asf(hv.y << 16), a);
    a = fmaf(cA.w, asf(hv.y & 0xFFFF0000u), a);
    a = fmaf(cB.x, asf(hv.z << 16), a);
    a = fmaf(cB.y, asf(hv.z & 0xFFFF0000u), a);
    a = fmaf(cB.z, asf(hv.w << 16), a);
    a = fmaf(cB.w, asf(hv.w & 0xFFFF0000u), a);
    return a;
}

// ---------------------------------------------------------------------------
// Projection: Hn[n][o][b] = sum_i x[n][i] * bases[b][i][o]   (bf16 out)
// Output dim split into OBLK-wide chunks (blockIdx.y) so LDS weight tile is
// 16KB -> 4 blocks/CU occupancy (was 64KB -> 2 blocks/CU).
// ---------------------------------------------------------------------------
template <int DOUT, int OBLK, bool RELU>
__launch_bounds__(256)
__global__ void project_kernel(const float* __restrict__ x,
                               const float* __restrict__ bases,
                               uint16_t* __restrict__ hn, int nNodes) {
    constexpr int SUBS = 256 / OBLK;
    constexpr int NPT  = 4;
    constexpr int TILE = SUBS * NPT;
    constexpr int XS   = HDIM + 1;

    __shared__ __align__(16) uint16_t Wl[HDIM * OBLK * NB];
    __shared__ __align__(16) float    Xl[TILE * XS];

    const int t  = threadIdx.x;
    const int o  = t % OBLK;
    const int ns = t / OBLK;
    const int o0 = blockIdx.y * OBLK;

    // Stage this chunk's weights: global [b][i][o0+oo] f32 -> LDS [i][oo][b] bf16
    for (int idx = t; idx < HDIM * OBLK * NB; idx += 256) {
        int b   = idx / (HDIM * OBLK);
        int rem = idx - b * (HDIM * OBLK);
        int i   = rem / OBLK;
        int oo  = rem - i * OBLK;
        Wl[(i * OBLK + oo) * NB + b] = f2bf(bases[((size_t)b * HDIM + i) * DOUT + o0 + oo]);
    }

    const int numTiles = (nNodes + TILE - 1) / TILE;
    for (int tile = blockIdx.x; tile < numTiles; tile += gridDim.x) {
        const int n0 = tile * TILE;
        __syncthreads();
        for (int idx = t; idx < TILE * HDIM; idx += 256) {
            int nn = idx / HDIM, i = idx - nn * HDIM;
            int g = n0 + nn;
            float v = (g < nNodes) ? x[(size_t)g * HDIM + i] : 0.f;
            if (RELU) v = fmaxf(v, 0.f);
            Xl[nn * XS + i] = v;
        }
        __syncthreads();

        float acc[NPT][NB];
#pragma unroll
        for (int k = 0; k < NPT; k++)
#pragma unroll
            for (int b = 0; b < NB; b++) acc[k][b] = 0.f;

#pragma unroll 8
        for (int i = 0; i < HDIM; i++) {
            const uint4 wv = *reinterpret_cast<const uint4*>(Wl + (i * OBLK + o) * NB);
            float w[NB];
            w[0] = asf(wv.x << 16); w[1] = asf(wv.x & 0xFFFF0000u);
            w[2] = asf(wv.y << 16); w[3] = asf(wv.y & 0xFFFF0000u);
            w[4] = asf(wv.z << 16); w[5] = asf(wv.z & 0xFFFF0000u);
            w[6] = asf(wv.w << 16); w[7] = asf(wv.w & 0xFFFF0000u);
#pragma unroll
            for (int k = 0; k < NPT; k++) {
                const float xv = Xl[(k * SUBS + ns) * XS + i];
#pragma unroll
                for (int b = 0; b < NB; b++) acc[k][b] = fmaf(xv, w[b], acc[k][b]);
            }
        }

#pragma unroll
        for (int k = 0; k < NPT; k++) {
            const int g = n0 + k * SUBS + ns;
            if (g < nNodes) {
                uint4 pv;
                pv.x = pack2(acc[k][0], acc[k][1]);
                pv.y = pack2(acc[k][2], acc[k][3]);
                pv.z = pack2(acc[k][4], acc[k][5]);
                pv.w = pack2(acc[k][6], acc[k][7]);
                *reinterpret_cast<uint4*>(hn + ((size_t)g * DOUT + o0 + o) * NB) = pv;
            }
        }
    }
}

// ---------------------------------------------------------------------------
// CSR build: histogram by dst -> exclusive scan -> scatter packed edge recs
// ---------------------------------------------------------------------------
__global__ void zero_kernel(int* __restrict__ p, int n) {
    for (int i = (int)(blockIdx.x * blockDim.x + threadIdx.x); i < n;
         i += (int)(gridDim.x * blockDim.x)) p[i] = 0;
}

__global__ void hist_kernel(const int* __restrict__ dst, int* __restrict__ cnt, int nE) {
    for (int e = (int)(blockIdx.x * blockDim.x + threadIdx.x); e < nE;
         e += (int)(gridDim.x * blockDim.x)) atomicAdd(&cnt[dst[e]], 1);
}

#define SCAN_B 512
__launch_bounds__(SCAN_B)
__global__ void scan_partial_kernel(const int* __restrict__ cnt, int* __restrict__ bsum, int n) {
    __shared__ int sh[SCAN_B];
    int id = (int)(blockIdx.x * SCAN_B + threadIdx.x);
    sh[threadIdx.x] = (id < n) ? cnt[id] : 0;
    __syncthreads();
    for (int off = SCAN_B / 2; off > 0; off >>= 1) {
        if ((int)threadIdx.x < off) sh[threadIdx.x] += sh[threadIdx.x + off];
        __syncthreads();
    }
    if (threadIdx.x == 0) bsum[blockIdx.x] = sh[0];
}

__global__ void scan_base_kernel(const int* __restrict__ bsum, int* __restrict__ bbase,
                                 int* __restrict__ offs, int nblk, int nNodes) {
    int run = 0;
    for (int i = 0; i < nblk; i++) { bbase[i] = run; run += bsum[i]; }
    offs[nNodes] = run;
}

__launch_bounds__(SCAN_B)
__global__ void scan_final_kernel(int* __restrict__ cnt, const int* __restrict__ bbase,
                                  int* __restrict__ offs, int n) {
    __shared__ int sh[SCAN_B];
    int id = (int)(blockIdx.x * SCAN_B + threadIdx.x);
    int v = (id < n) ? cnt[id] : 0;
    sh[threadIdx.x] = v;
    __syncthreads();
    for (int off = 1; off < SCAN_B; off <<= 1) {
        int tmp = ((int)threadIdx.x >= off) ? sh[threadIdx.x - off] : 0;
        __syncthreads();
        sh[threadIdx.x] += tmp;
        __syncthreads();
    }
    if (id < n) {
        int excl = sh[threadIdx.x] - v + bbase[blockIdx.x];
        offs[id] = excl;
        cnt[id]  = excl;   // becomes the scatter cursor
    }
}

__global__ void scatter_kernel(const int* __restrict__ src, const int* __restrict__ dst,
                               const int* __restrict__ et, const float* __restrict__ norm,
                               int* __restrict__ cursor, uint4* __restrict__ rec, int nE) {
    for (int e = (int)(blockIdx.x * blockDim.x + threadIdx.x); e < nE;
         e += (int)(gridDim.x * blockDim.x)) {
        int p = atomicAdd(&cursor[dst[e]], 1);
        rec[p] = make_uint4((uint32_t)src[e], (uint32_t)et[e], asu(norm[e]), 0u);
    }
}

// ---------------------------------------------------------------------------
// CSR aggregation, DOUT=64: one wave per dst node, NO atomics.
// h[d] = bias + sum_j norm_j * sum_b coeff[r_j,b] * Hn[src_j, :, b]
// ---------------------------------------------------------------------------
__launch_bounds__(256)
__global__ void csr_edge64_kernel(const uint16_t* __restrict__ hn,
                                  const float* __restrict__ coeff,
                                  const int* __restrict__ offs,
                                  const uint4* __restrict__ rec,
                                  const float* __restrict__ bias,
                                  float* __restrict__ out, int nNodes) {
    const int lane = threadIdx.x & 63;
    const int wid  = (int)((blockIdx.x * blockDim.x + threadIdx.x) >> 6);
    const int nw   = (int)((gridDim.x * blockDim.x) >> 6);
    const float bs = bias[lane];
    for (int d = wid; d < nNodes; d += nw) {
        const int j0 = offs[d], j1 = offs[d + 1];
        float acc = 0.f;
        int j = j0;
        for (; j + 2 <= j1; j += 2) {
            const uint4 r0 = rec[j], r1 = rec[j + 1];
            const uint4 h0 = *reinterpret_cast<const uint4*>(hn + ((size_t)r0.x * HDIM + lane) * NB);
            const uint4 h1 = *reinterpret_cast<const uint4*>(hn + ((size_t)r1.x * HDIM + lane) * NB);
            const float4 cA0 = *reinterpret_cast<const float4*>(coeff + r0.y * NB);
            const float4 cB0 = *reinterpret_cast<const float4*>(coeff + r0.y * NB + 4);
            const float4 cA1 = *reinterpret_cast<const float4*>(coeff + r1.y * NB);
            const float4 cB1 = *reinterpret_cast<const float4*>(coeff + r1.y * NB + 4);
            acc = fmaf(asf(r0.z), dot8(cA0, cB0, h0), acc);
            acc = fmaf(asf(r1.z), dot8(cA1, cB1, h1), acc);
        }
        if (j < j1) {
            const uint4 r0 = rec[j];
            const uint4 h0 = *reinterpret_cast<const uint4*>(hn + ((size_t)r0.x * HDIM + lane) * NB);
            const float4 cA0 = *reinterpret_cast<const float4*>(coeff + r0.y * NB);
            const float4 cB0 = *reinterpret_cast<const float4*>(coeff + r0.y * NB + 4);
            acc = fmaf(asf(r0.z), dot8(cA0, cB0, h0), acc);
        }
        out[(size_t)d * HDIM + lane] = acc + bs;
    }
}

// CSR aggregation, DOUT=16: wave per node; lanes = (k=lane>>4 edge-slot, o=lane&15).
__launch_bounds__(256)
__global__ void csr_edge16_kernel(const uint16_t* __restrict__ hn,
                                  const float* __restrict__ coeff,
                                  const int* __restrict__ offs,
                                  const uint4* __restrict__ rec,
                                  const float* __restrict__ bias,
                                  float* __restrict__ out, int nNodes) {
    const int lane = threadIdx.x & 63;
    const int o    = lane & 15;
    const int k    = lane >> 4;
    const int wid  = (int)((blockIdx.x * blockDim.x + threadIdx.x) >> 6);
    const int nw   = (int)((gridDim.x * blockDim.x) >> 6);
    const float bs = bias[o];
    for (int d = wid; d < nNodes; d += nw) {
        const int j0 = offs[d], j1 = offs[d + 1];
        float acc = 0.f;
        for (int j = j0 + k; j < j1; j += 4) {
            const uint4 r0 = rec[j];
            const uint4 h0 = *reinterpret_cast<const uint4*>(hn + ((size_t)r0.x * ODIM + o) * NB);
            const float4 cA0 = *reinterpret_cast<const float4*>(coeff + r0.y * NB);
            const float4 cB0 = *reinterpret_cast<const float4*>(coeff + r0.y * NB + 4);
            acc = fmaf(asf(r0.z), dot8(cA0, cB0, h0), acc);
        }
        acc += __shfl_xor(acc, 16, 64);
        acc += __shfl_xor(acc, 32, 64);
        if (lane < 16) out[(size_t)d * ODIM + o] = acc + bs;
    }
}

// ---------------------------------------------------------------------------
// Fallback (ws too small for CSR): atomic edge kernels + bias fill
// ---------------------------------------------------------------------------
__launch_bounds__(256)
__global__ void edge_kernel64(const uint16_t* __restrict__ hn,
                              const float* __restrict__ coeff,
                              const int* __restrict__ src, const int* __restrict__ dst,
                              const int* __restrict__ et, const float* __restrict__ norm,
                              float* __restrict__ out, int nEdges) {
    const int lane = threadIdx.x & 63;
    const int wid  = (int)((blockIdx.x * blockDim.x + threadIdx.x) >> 6);
    const int nw   = (int)((gridDim.x * blockDim.x) >> 6);
    for (int e = wid; e < nEdges; e += nw) {
        const int s = src[e], d = dst[e], r = et[e];
        const float nm = norm[e];
        const float4 cA = *reinterpret_cast<const float4*>(coeff + r * NB);
        const float4 cB = *reinterpret_cast<const float4*>(coeff + r * NB + 4);
        const uint4 hv = *reinterpret_cast<const uint4*>(hn + ((size_t)s * HDIM + lane) * NB);
        unsafeAtomicAdd(out + (size_t)d * HDIM + lane, nm * dot8(cA, cB, hv));
    }
}

__launch_bounds__(256)
__global__ void edge_kernel16(const uint16_t* __restrict__ hn,
                              const float* __restrict__ coeff,
                              const int* __restrict__ src, const int* __restrict__ dst,
                              const int* __restrict__ et, const float* __restrict__ norm,
                              float* __restrict__ out, int nEdges) {
    const int g    = (int)(blockIdx.x * blockDim.x + threadIdx.x);
    const int lane = g & 15;
    const int qid  = g >> 4;
    const int nq   = (int)((gridDim.x * blockDim.x) >> 4);
    for (int e = qid; e < nEdges; e += nq) {
        const int s = src[e], d = dst[e], r = et[e];
        const float nm = norm[e];
        const float4 cA = *reinterpret_cast<const float4*>(coeff + r * NB);
        const float4 cB = *reinterpret_cast<const float4*>(coeff + r * NB + 4);
        const uint4 hv = *reinterpret_cast<const uint4*>(hn + ((size_t)s * ODIM + lane) * NB);
        unsafeAtomicAdd(out + (size_t)d * ODIM + lane, nm * dot8(cA, cB, hv));
    }
}

template <int D>
__global__ void fill_bias_kernel(float* __restrict__ out, const float* __restrict__ bias,
                                 int total) {
    const int stride = (int)(gridDim.x * blockDim.x);
    for (int i = (int)(blockIdx.x * blockDim.x + threadIdx.x); i < total; i += stride)
        out[i] = bias[i & (D - 1)];
}

extern "C" void kernel_launch(void* const* d_in, const int* in_sizes, int n_in,
                              void* d_out, int out_size, void* d_ws, size_t ws_size,
                              hipStream_t stream) {
    const float* feats  = (const float*)d_in[0];
    const float* coeff0 = (const float*)d_in[1];
    const float* bases0 = (const float*)d_in[2];
    const float* bias0  = (const float*)d_in[3];
    const float* coeff1 = (const float*)d_in[4];
    const float* bases1 = (const float*)d_in[5];
    const float* bias1  = (const float*)d_in[6];
    const float* coeff2 = (const float*)d_in[7];
    const float* bases2 = (const float*)d_in[8];
    const float* bias2  = (const float*)d_in[9];
    const int*   src    = (const int*)d_in[10];
    const int*   dst    = (const int*)d_in[11];
    const int*   etype  = (const int*)d_in[12];
    const float* norm   = (const float*)d_in[13];
    float* out = (float*)d_out;

    char* base = (char*)d_ws;
    uint16_t* hn = (uint16_t*)base;                                    // 102,400,000 B
    float*    h  = (float*)(base + (size_t)NNODES * HDIM * NB * 2);    //  25,600,000 B

    const int nblk = (NNODES + SCAN_B - 1) / SCAN_B;                   // 196
    const size_t OFF_OFFS  = 128000000;
    const size_t OFF_CURS  = OFF_OFFS + 400016;
    const size_t OFF_BSUM  = OFF_CURS + 400016;
    const size_t OFF_BBASE = OFF_BSUM + 1024;
    const size_t OFF_REC   = OFF_BBASE + 1024;
    const size_t NEEDED    = OFF_REC + (size_t)NEDGES * 16;            // ~144.8 MB

    if (ws_size >= NEEDED) {
        int*   offs   = (int*)(base + OFF_OFFS);
        int*   curs   = (int*)(base + OFF_CURS);
        int*   bsum   = (int*)(base + OFF_BSUM);
        int*   bbase  = (int*)(base + OFF_BBASE);
        uint4* rec    = (uint4*)(base + OFF_REC);

        // ---- CSR build (graph identical across layers; built once per call)
        hipLaunchKernelGGL(zero_kernel, dim3(256), dim3(256), 0, stream, curs, NNODES);
        hipLaunchKernelGGL(hist_kernel, dim3(2048), dim3(256), 0, stream, dst, curs, NEDGES);
        hipLaunchKernelGGL(scan_partial_kernel, dim3(nblk), dim3(SCAN_B), 0, stream, curs, bsum, NNODES);
        hipLaunchKernelGGL(scan_base_kernel, dim3(1), dim3(1), 0, stream, bsum, bbase, offs, nblk, NNODES);
        hipLaunchKernelGGL(scan_final_kernel, dim3(nblk), dim3(SCAN_B), 0, stream, curs, bbase, offs, NNODES);
        hipLaunchKernelGGL(scatter_kernel, dim3(2048), dim3(256), 0, stream,
                           src, dst, etype, norm, curs, rec, NEDGES);

        // ---- Layer 0
        hipLaunchKernelGGL((project_kernel<64, 16, false>), dim3(1024, 4), dim3(256), 0, stream,
                           feats, bases0, hn, NNODES);
        hipLaunchKernelGGL(csr_edge64_kernel, dim3(4096), dim3(256), 0, stream,
                           hn, coeff0, offs, rec, bias0, h, NNODES);
        // ---- Layer 1
        hipLaunchKernelGGL((project_kernel<64, 16, true>), dim3(1024, 4), dim3(256), 0, stream,
                           h, bases1, hn, NNODES);
        hipLaunchKernelGGL(csr_edge64_kernel, dim3(4096), dim3(256), 0, stream,
                           hn, coeff1, offs, rec, bias1, h, NNODES);
        // ---- Layer 2
        hipLaunchKernelGGL((project_kernel<16, 16, true>), dim3(1024, 1), dim3(256), 0, stream,
                           h, bases2, hn, NNODES);
        hipLaunchKernelGGL(csr_edge16_kernel, dim3(4096), dim3(256), 0, stream,
                           hn, coeff2, offs, rec, bias2, out, NNODES);
    } else {
        // ---- Fallback: atomic scatter path (round-1 structure)
        hipLaunchKernelGGL((project_kernel<64, 16, false>), dim3(1024, 4), dim3(256), 0, stream,
                           feats, bases0, hn, NNODES);
        hipLaunchKernelGGL((fill_bias_kernel<64>), dim3(1024), dim3(256), 0, stream,
                           h, bias0, NNODES * HDIM);
        hipLaunchKernelGGL(edge_kernel64, dim3(4096), dim3(256), 0, stream,
                           hn, coeff0, src, dst, etype, norm, h, NEDGES);

        hipLaunchKernelGGL((project_kernel<64, 16, true>), dim3(1024, 4), dim3(256), 0, stream,
                           h, bases1, hn, NNODES);
        hipLaunchKernelGGL((fill_bias_kernel<64>), dim3(1024), dim3(256), 0, stream,
                           h, bias1, NNODES * HDIM);
        hipLaunchKernelGGL(edge_kernel64, dim3(4096), dim3(256), 0, stream,
                           hn, coeff1, src, dst, etype, norm, h, NEDGES);

        hipLaunchKernelGGL((project_kernel<16, 16, true>), dim3(1024, 1), dim3(256), 0, stream,
                           h, bases2, hn, NNODES);
        hipLaunchKernelGGL((fill_bias_kernel<16>), dim3(1024), dim3(256), 0, stream,
                           out, bias2, NNODES * ODIM);
        hipLaunchKernelGGL(edge_kernel16, dim3(4096), dim3(256), 0, stream,
                           hn, coeff2, src, dst, etype, norm, out, NEDGES);
    }
}

// Round 4
// 719.252 us; speedup vs baseline: 1.3046x; 1.1580x over previous
//
#include <hip/hip_runtime.h>
#include <hip/hip_bf16.h>
#include <cstdint>

#define NNODES 100000
#define NEDGES 1000000
#define HDIM 64
#define ODIM 16
#define NB 8
#define KDIM (HDIM * NB)   // 512 = GEMM inner dim, k = i*8 + b

typedef short short8 __attribute__((ext_vector_type(8)));
typedef float f32x4  __attribute__((ext_vector_type(4)));
union FragU { uint4 u; short8 s; };

__device__ __forceinline__ float asf(uint32_t u) { float f; __builtin_memcpy(&f, &u, 4); return f; }
__device__ __forceinline__ uint32_t asu(float f) { uint32_t u; __builtin_memcpy(&u, &f, 4); return u; }
__device__ __forceinline__ uint16_t f2bf(float f) {
    uint32_t x = asu(f);
    return (uint16_t)((x + 0x7FFFu + ((x >> 16) & 1u)) >> 16);
}
__device__ __forceinline__ uint32_t pack2(float lo, float hi) {
    return (uint32_t)f2bf(lo) | ((uint32_t)f2bf(hi) << 16);
}

// ---------------------------------------------------------------------------
// cast: f32 feats -> bf16 x  (4 elems/thread)
// ---------------------------------------------------------------------------
__global__ void cast_kernel(const float* __restrict__ in, uint16_t* __restrict__ out, int n4) {
    const int stride = (int)(gridDim.x * blockDim.x);
    for (int idx = (int)(blockIdx.x * blockDim.x + threadIdx.x); idx < n4; idx += stride) {
        float4 v = reinterpret_cast<const float4*>(in)[idx];
        uint2 p;
        p.x = pack2(v.x, v.y);
        p.y = pack2(v.z, v.w);
        reinterpret_cast<uint2*>(out)[idx] = p;
    }
}

// ---------------------------------------------------------------------------
// CSR build: histogram by dst -> exclusive scan -> scatter packed edge recs
// ---------------------------------------------------------------------------
__global__ void zero_kernel(int* __restrict__ p, int n) {
    for (int i = (int)(blockIdx.x * blockDim.x + threadIdx.x); i < n;
         i += (int)(gridDim.x * blockDim.x)) p[i] = 0;
}

__global__ void hist_kernel(const int* __restrict__ dst, int* __restrict__ cnt, int nE) {
    for (int e = (int)(blockIdx.x * blockDim.x + threadIdx.x); e < nE;
         e += (int)(gridDim.x * blockDim.x)) atomicAdd(&cnt[dst[e]], 1);
}

#define SCAN_B 512
__launch_bounds__(SCAN_B)
__global__ void scan_partial_kernel(const int* __restrict__ cnt, int* __restrict__ bsum, int n) {
    __shared__ int sh[SCAN_B];
    int id = (int)(blockIdx.x * SCAN_B + threadIdx.x);
    sh[threadIdx.x] = (id < n) ? cnt[id] : 0;
    __syncthreads();
    for (int off = SCAN_B / 2; off > 0; off >>= 1) {
        if ((int)threadIdx.x < off) sh[threadIdx.x] += sh[threadIdx.x + off];
        __syncthreads();
    }
    if (threadIdx.x == 0) bsum[blockIdx.x] = sh[0];
}

__global__ void scan_base_kernel(const int* __restrict__ bsum, int* __restrict__ bbase,
                                 int* __restrict__ offs, int nblk, int nNodes) {
    int run = 0;
    for (int i = 0; i < nblk; i++) { bbase[i] = run; run += bsum[i]; }
    offs[nNodes] = run;
}

__launch_bounds__(SCAN_B)
__global__ void scan_final_kernel(int* __restrict__ cnt, const int* __restrict__ bbase,
                                  int* __restrict__ offs, int n) {
    __shared__ int sh[SCAN_B];
    int id = (int)(blockIdx.x * SCAN_B + threadIdx.x);
    int v = (id < n) ? cnt[id] : 0;
    sh[threadIdx.x] = v;
    __syncthreads();
    for (int off = 1; off < SCAN_B; off <<= 1) {
        int tmp = ((int)threadIdx.x >= off) ? sh[threadIdx.x - off] : 0;
        __syncthreads();
        sh[threadIdx.x] += tmp;
        __syncthreads();
    }
    if (id < n) {
        int excl = sh[threadIdx.x] - v + bbase[blockIdx.x];
        offs[id] = excl;
        cnt[id]  = excl;   // becomes the scatter cursor
    }
}

__global__ void scatter_kernel(const int* __restrict__ src, const int* __restrict__ dst,
                               const int* __restrict__ et, const float* __restrict__ norm,
                               int* __restrict__ cursor, uint4* __restrict__ rec, int nE) {
    for (int e = (int)(blockIdx.x * blockDim.x + threadIdx.x); e < nE;
         e += (int)(gridDim.x * blockDim.x)) {
        int p = atomicAdd(&cursor[dst[e]], 1);
        rec[p] = make_uint4((uint32_t)src[e], (uint32_t)et[e], asu(norm[e]), 0u);
    }
}

// ---------------------------------------------------------------------------
// Input-space aggregation: G[d][i][b] = sum_{e in in(d)} norm_e*coeff[r_e,b]*x[src_e,i]
// One wave per dst node; lane = i; 8 f32 accums/lane; bf16 out (k = i*8+b).
// Gather = 128 B/edge from a 12.8 MB array (L2-resident).
// ---------------------------------------------------------------------------
__launch_bounds__(256)
__global__ void csr_agg_kernel(const uint16_t* __restrict__ x,
                               const float* __restrict__ coeff,
                               const int* __restrict__ offs,
                               const uint4* __restrict__ rec,
                               uint16_t* __restrict__ G, int nNodes) {
    const int lane = threadIdx.x & 63;
    const int wid  = (int)((blockIdx.x * blockDim.x + threadIdx.x) >> 6);
    const int nw   = (int)((gridDim.x * blockDim.x) >> 6);
    for (int d = wid; d < nNodes; d += nw) {
        const int j0 = offs[d], j1 = offs[d + 1];
        float acc[NB];
#pragma unroll
        for (int b = 0; b < NB; b++) acc[b] = 0.f;
        int j = j0;
        for (; j + 2 <= j1; j += 2) {
            const uint4 r0 = rec[j], r1 = rec[j + 1];
            const float xv0 = asf((uint32_t)x[(size_t)r0.x * HDIM + lane] << 16);
            const float xv1 = asf((uint32_t)x[(size_t)r1.x * HDIM + lane] << 16);
            const float4 cA0 = *reinterpret_cast<const float4*>(coeff + r0.y * NB);
            const float4 cB0 = *reinterpret_cast<const float4*>(coeff + r0.y * NB + 4);
            const float4 cA1 = *reinterpret_cast<const float4*>(coeff + r1.y * NB);
            const float4 cB1 = *reinterpret_cast<const float4*>(coeff + r1.y * NB + 4);
            const float xs0 = asf(r0.z) * xv0;
            const float xs1 = asf(r1.z) * xv1;
            acc[0] = fmaf(cA0.x, xs0, acc[0]); acc[1] = fmaf(cA0.y, xs0, acc[1]);
            acc[2] = fmaf(cA0.z, xs0, acc[2]); acc[3] = fmaf(cA0.w, xs0, acc[3]);
            acc[4] = fmaf(cB0.x, xs0, acc[4]); acc[5] = fmaf(cB0.y, xs0, acc[5]);
            acc[6] = fmaf(cB0.z, xs0, acc[6]); acc[7] = fmaf(cB0.w, xs0, acc[7]);
            acc[0] = fmaf(cA1.x, xs1, acc[0]); acc[1] = fmaf(cA1.y, xs1, acc[1]);
            acc[2] = fmaf(cA1.z, xs1, acc[2]); acc[3] = fmaf(cA1.w, xs1, acc[3]);
            acc[4] = fmaf(cB1.x, xs1, acc[4]); acc[5] = fmaf(cB1.y, xs1, acc[5]);
            acc[6] = fmaf(cB1.z, xs1, acc[6]); acc[7] = fmaf(cB1.w, xs1, acc[7]);
        }
        if (j < j1) {
            const uint4 r0 = rec[j];
            const float xv0 = asf((uint32_t)x[(size_t)r0.x * HDIM + lane] << 16);
            const float4 cA0 = *reinterpret_cast<const float4*>(coeff + r0.y * NB);
            const float4 cB0 = *reinterpret_cast<const float4*>(coeff + r0.y * NB + 4);
            const float xs0 = asf(r0.z) * xv0;
            acc[0] = fmaf(cA0.x, xs0, acc[0]); acc[1] = fmaf(cA0.y, xs0, acc[1]);
            acc[2] = fmaf(cA0.z, xs0, acc[2]); acc[3] = fmaf(cA0.w, xs0, acc[3]);
            acc[4] = fmaf(cB0.x, xs0, acc[4]); acc[5] = fmaf(cB0.y, xs0, acc[5]);
            acc[6] = fmaf(cB0.z, xs0, acc[6]); acc[7] = fmaf(cB0.w, xs0, acc[7]);
        }
        uint4 pv;
        pv.x = pack2(acc[0], acc[1]);
        pv.y = pack2(acc[2], acc[3]);
        pv.z = pack2(acc[4], acc[5]);
        pv.w = pack2(acc[6], acc[7]);
        *reinterpret_cast<uint4*>(G + (size_t)d * KDIM + lane * NB) = pv;
    }
}

// ---------------------------------------------------------------------------
// MFMA GEMM: [N,512] bf16 (G) x [512,DOUT] bf16 (bases, swizzled to B-frag
// order in LDS) -> DOUT per node. mfma_f32_16x16x32_bf16:
//   A[m=lane&15][k=(lane>>4)*8+j], B[k=(lane>>4)*8+j][n=lane&15],
//   C col=lane&15, row=(lane>>4)*4+reg.
// Block = 4 waves, 64-node tile; wave w owns nodes n0+w*16..+15, all DOUT.
// ---------------------------------------------------------------------------
__launch_bounds__(256)
__global__ void proj_hidden_kernel(const uint16_t* __restrict__ G,
                                   const float* __restrict__ bases,
                                   const float* __restrict__ bias,
                                   uint16_t* __restrict__ xout, int nNodes) {
    constexpr int OT = HDIM / 16;       // 4 o-tiles
    __shared__ __align__(16) uint16_t Wf[16 * OT * 64 * 8];   // 64 KB

    const int t    = (int)threadIdx.x;
    const int lane = t & 63;
    const int w    = t >> 6;
    const int q    = lane >> 4;
    const int c    = lane & 15;

    // Stage bases into B-fragment order: Wf[((kb*OT+ot)*64+lane)*8+j] =
    //   bf16(bases[b][i][o]) with k=kb*32+q*8+j, o=ot*16+c, i=k>>3, b=k&7.
    for (int idx = t; idx < 16 * OT * 64 * 8; idx += 256) {
        int j    = idx & 7;
        int ln   = (idx >> 3) & 63;
        int rest = idx >> 9;            // kb*OT + ot
        int ot   = rest & (OT - 1);
        int kb   = rest >> 2;
        int k    = kb * 32 + (ln >> 4) * 8 + j;
        int o    = ot * 16 + (ln & 15);
        int i    = k >> 3, b = k & 7;
        Wf[idx] = f2bf(bases[(size_t)(b * HDIM + i) * HDIM + o]);
    }
    __syncthreads();

    float bv[OT];
#pragma unroll
    for (int ot = 0; ot < OT; ot++) bv[ot] = bias[ot * 16 + c];

    const int nTiles = (nNodes + 63) / 64;
    for (int tile = blockIdx.x; tile < nTiles; tile += gridDim.x) {
        const int n0w = tile * 64 + w * 16;
        int arow = n0w + c;
        if (arow > nNodes - 1) arow = nNodes - 1;
        const uint16_t* gp = G + (size_t)arow * KDIM + q * 8;

        f32x4 acc[OT];
#pragma unroll
        for (int ot = 0; ot < OT; ot++) acc[ot] = {0.f, 0.f, 0.f, 0.f};

#pragma unroll
        for (int kb = 0; kb < 16; kb++) {
            FragU a;
            a.u = *reinterpret_cast<const uint4*>(gp + kb * 32);
#pragma unroll
            for (int ot = 0; ot < OT; ot++) {
                FragU b;
                b.u = *reinterpret_cast<const uint4*>(Wf + ((kb * OT + ot) * 64 + lane) * 8);
                acc[ot] = __builtin_amdgcn_mfma_f32_16x16x32_bf16(a.s, b.s, acc[ot], 0, 0, 0);
            }
        }

#pragma unroll
        for (int r = 0; r < 4; r++) {
            const int node = n0w + q * 4 + r;
            if (node < nNodes) {
#pragma unroll
                for (int ot = 0; ot < OT; ot++) {
                    float v = fmaxf(acc[ot][r] + bv[ot], 0.f);
                    xout[(size_t)node * HDIM + ot * 16 + c] = f2bf(v);
                }
            }
        }
    }
}

__launch_bounds__(256)
__global__ void proj_out_kernel(const uint16_t* __restrict__ G,
                                const float* __restrict__ bases,
                                const float* __restrict__ bias,
                                float* __restrict__ out, int nNodes) {
    __shared__ __align__(16) uint16_t Wf[16 * 64 * 8];   // 16 KB

    const int t    = (int)threadIdx.x;
    const int lane = t & 63;
    const int w    = t >> 6;
    const int q    = lane >> 4;
    const int c    = lane & 15;

    for (int idx = t; idx < 16 * 64 * 8; idx += 256) {
        int j  = idx & 7;
        int ln = (idx >> 3) & 63;
        int kb = idx >> 9;
        int k  = kb * 32 + (ln >> 4) * 8 + j;
        int o  = ln & 15;
        int i  = k >> 3, b = k & 7;
        Wf[idx] = f2bf(bases[(size_t)(b * HDIM + i) * ODIM + o]);
    }
    __syncthreads();

    const float bv = bias[c];

    const int nTiles = (nNodes + 63) / 64;
    for (int tile = blockIdx.x; tile < nTiles; tile += gridDim.x) {
        const int n0w = tile * 64 + w * 16;
        int arow = n0w + c;
        if (arow > nNodes - 1) arow = nNodes - 1;
        const uint16_t* gp = G + (size_t)arow * KDIM + q * 8;

        f32x4 acc = {0.f, 0.f, 0.f, 0.f};
#pragma unroll
        for (int kb = 0; kb < 16; kb++) {
            FragU a, b;
            a.u = *reinterpret_cast<const uint4*>(gp + kb * 32);
            b.u = *reinterpret_cast<const uint4*>(Wf + (kb * 64 + lane) * 8);
            acc = __builtin_amdgcn_mfma_f32_16x16x32_bf16(a.s, b.s, acc, 0, 0, 0);
        }

#pragma unroll
        for (int r = 0; r < 4; r++) {
            const int node = n0w + q * 4 + r;
            if (node < nNodes) out[(size_t)node * ODIM + c] = acc[r] + bv;
        }
    }
}

extern "C" void kernel_launch(void* const* d_in, const int* in_sizes, int n_in,
                              void* d_out, int out_size, void* d_ws, size_t ws_size,
                              hipStream_t stream) {
    const float* feats  = (const float*)d_in[0];
    const float* coeff0 = (const float*)d_in[1];
    const float* bases0 = (const float*)d_in[2];
    const float* bias0  = (const float*)d_in[3];
    const float* coeff1 = (const float*)d_in[4];
    const float* bases1 = (const float*)d_in[5];
    const float* bias1  = (const float*)d_in[6];
    const float* coeff2 = (const float*)d_in[7];
    const float* bases2 = (const float*)d_in[8];
    const float* bias2  = (const float*)d_in[9];
    const int*   src    = (const int*)d_in[10];
    const int*   dst    = (const int*)d_in[11];
    const int*   etype  = (const int*)d_in[12];
    const float* norm   = (const float*)d_in[13];
    float* out = (float*)d_out;

    char* base = (char*)d_ws;
    // layout: G 102.4MB | x 12.8MB | offs | cursor | bsum | bbase | rec 16MB
    uint16_t* G = (uint16_t*)base;
    uint16_t* x = (uint16_t*)(base + (size_t)NNODES * KDIM * 2);       // +102,400,000
    const size_t OFF_OFFS  = 115200000;
    const size_t OFF_CURS  = OFF_OFFS + 400016;
    const size_t OFF_BSUM  = OFF_CURS + 400016;
    const size_t OFF_BBASE = OFF_BSUM + 1024;
    const size_t OFF_REC   = OFF_BBASE + 1024;
    int*   offs  = (int*)(base + OFF_OFFS);
    int*   curs  = (int*)(base + OFF_CURS);
    int*   bsum  = (int*)(base + OFF_BSUM);
    int*   bbase = (int*)(base + OFF_BBASE);
    uint4* rec   = (uint4*)(base + OFF_REC);

    const int nblk = (NNODES + SCAN_B - 1) / SCAN_B;

    // ---- CSR build (graph identical across layers; built once per call)
    hipLaunchKernelGGL(zero_kernel, dim3(256), dim3(256), 0, stream, curs, NNODES);
    hipLaunchKernelGGL(hist_kernel, dim3(2048), dim3(256), 0, stream, dst, curs, NEDGES);
    hipLaunchKernelGGL(scan_partial_kernel, dim3(nblk), dim3(SCAN_B), 0, stream, curs, bsum, NNODES);
    hipLaunchKernelGGL(scan_base_kernel, dim3(1), dim3(1), 0, stream, bsum, bbase, offs, nblk, NNODES);
    hipLaunchKernelGGL(scan_final_kernel, dim3(nblk), dim3(SCAN_B), 0, stream, curs, bbase, offs, NNODES);
    hipLaunchKernelGGL(scatter_kernel, dim3(2048), dim3(256), 0, stream,
                       src, dst, etype, norm, curs, rec, NEDGES);

    // ---- x0 = bf16(feats)
    hipLaunchKernelGGL(cast_kernel, dim3(2048), dim3(256), 0, stream,
                       feats, x, NNODES * HDIM / 4);

    // ---- Layer 0
    hipLaunchKernelGGL(csr_agg_kernel, dim3(1024), dim3(256), 0, stream,
                       x, coeff0, offs, rec, G, NNODES);
    hipLaunchKernelGGL(proj_hidden_kernel, dim3(512), dim3(256), 0, stream,
                       G, bases0, bias0, x, NNODES);
    // ---- Layer 1
    hipLaunchKernelGGL(csr_agg_kernel, dim3(1024), dim3(256), 0, stream,
                       x, coeff1, offs, rec, G, NNODES);
    hipLaunchKernelGGL(proj_hidden_kernel, dim3(512), dim3(256), 0, stream,
                       G, bases1, bias1, x, NNODES);
    // ---- Layer 2
    hipLaunchKernelGGL(csr_agg_kernel, dim3(1024), dim3(256), 0, stream,
                       x, coeff2, offs, rec, G, NNODES);
    hipLaunchKernelGGL(proj_out_kernel, dim3(512), dim3(256), 0, stream,
                       G, bases2, bias2, out, NNODES);
}